// Round 1
// baseline (11835.992 us; speedup 1.0000x reference)
//
#include <hip/hip_runtime.h>
#include <math.h>

#define TT 1024
#define NB 64
#define NSTEPS 16
#define CH 16
#define SMC 10
#define NCLS 10
#define JIT 1e-4f

// ---------------- Btask = W W^T + diag(softplus(v)) ----------------
__global__ __launch_bounds__(256) void k_btask(const float* __restrict__ W,
                                               const float* __restrict__ v,
                                               float* __restrict__ Bt) {
    int t = threadIdx.x;
    for (int e = t; e < 17 * 17; e += 256) {
        int i = e / 17, j = e % 17;
        float s = 0.f;
        for (int r = 0; r < 3; r++) s += W[i * 3 + r] * W[j * 3 + r];
        if (i == j) s += log1pf(expf(v[i]));
        Bt[e] = s;
    }
}

// ---------------- Kxx build (lower tiles only) ----------------
__global__ __launch_bounds__(256) void k_build_kxx(const float* __restrict__ x,
                                                   const int* __restrict__ itr,
                                                   const float* __restrict__ lsp,
                                                   const float* __restrict__ noisep,
                                                   const float* __restrict__ Bt,
                                                   float* __restrict__ A, int b0) {
    int bi = blockIdx.x, bj = blockIdx.y, bz = blockIdx.z;
    if (bj > bi) return;
    int b = b0 + bz;
    __shared__ float sxi[128], sxj[128], Btl[289];
    __shared__ int sii[128], sij[128];
    int t = threadIdx.x;
    if (t < 128) { sxi[t] = x[b * TT + bi * 128 + t]; sii[t] = itr[b * TT + bi * 128 + t]; }
    else { int u = t - 128; sxj[u] = x[b * TT + bj * 128 + u]; sij[u] = itr[b * TT + bj * 128 + u]; }
    for (int e = t; e < 289; e += 256) Btl[e] = Bt[e];
    __syncthreads();
    float invls = 1.0f / lsp[0];
    float n2 = noisep[0] * noisep[0] + JIT;
    float* Ab = A + (size_t)bz * TT * TT;
    for (int l = 0; l < 64; l++) {
        int e = l * 256 + t;
        int r = e >> 7, c = e & 127;
        float d = (sxi[r] - sxj[c]) * invls;
        float kv = expf(-0.5f * d * d) * Btl[sii[r] * 17 + sij[c]];
        int gi = bi * 128 + r, gj = bj * 128 + c;
        if (gi == gj) kv += n2;
        Ab[(size_t)gi * TT + gj] = kv;
    }
}

// ---------------- G = Ksx^T build ([train j][test i]) ----------------
__global__ __launch_bounds__(256) void k_build_g(const float* __restrict__ xs,
                                                 const float* __restrict__ x,
                                                 const int* __restrict__ ite,
                                                 const int* __restrict__ itr,
                                                 const float* __restrict__ lsp,
                                                 const float* __restrict__ Bt,
                                                 float* __restrict__ G, int b0) {
    int bj = blockIdx.x, bi = blockIdx.y, bz = blockIdx.z;
    int b = b0 + bz;
    __shared__ float sxr[128], sxc[128], Btl[289];
    __shared__ int sir[128], sic[128];
    int t = threadIdx.x;
    if (t < 128) { sxr[t] = x[b * TT + bj * 128 + t]; sir[t] = itr[b * TT + bj * 128 + t]; }
    else { int u = t - 128; sxc[u] = xs[b * TT + bi * 128 + u]; sic[u] = ite[b * TT + bi * 128 + u]; }
    for (int e = t; e < 289; e += 256) Btl[e] = Bt[e];
    __syncthreads();
    float invls = 1.0f / lsp[0];
    float* Gb = G + (size_t)bz * TT * TT;
    for (int l = 0; l < 64; l++) {
        int e = l * 256 + t;
        int r = e >> 7, c = e & 127;
        float d = (sxc[c] - sxr[r]) * invls;
        float kv = expf(-0.5f * d * d) * Btl[sic[c] * 17 + sir[r]];
        Gb[(size_t)(bj * 128 + r) * TT + bi * 128 + c] = kv;
    }
}

// ---------------- Cholesky: 64x64 diagonal block factor ----------------
__global__ __launch_bounds__(64) void k_chol_diag(float* __restrict__ A, int k) {
    int bz = blockIdx.x;
    float* Ab = A + (size_t)bz * TT * TT;
    int kb = k * NB;
    __shared__ float s[NB][NB + 1];
    __shared__ float invl[NB];
    int t = threadIdx.x;
    for (int l = 0; l < NB; l++) s[l][t] = Ab[(size_t)(kb + l) * TT + kb + t];
    __syncthreads();
    for (int j = 0; j < NB; j++) {
        if (t == j) { float d = sqrtf(s[j][j]); s[j][j] = d; invl[j] = 1.0f / d; }
        __syncthreads();
        if (t > j) s[t][j] *= invl[j];
        __syncthreads();
        if (t > j) {
            float lij = s[t][j];
            for (int p = j + 1; p <= t; p++) s[t][p] -= lij * s[p][j];
        }
        __syncthreads();
    }
    for (int l = 0; l < NB; l++) Ab[(size_t)(kb + l) * TT + kb + t] = s[l][t];
}

// ---------------- Cholesky: panel TRSM (64 rows per block) ----------------
__global__ __launch_bounds__(64) void k_chol_trsm(float* __restrict__ A, int k) {
    int bz = blockIdx.y;
    float* Ab = A + (size_t)bz * TT * TT;
    int kb = k * NB;
    int r0 = kb + NB + blockIdx.x * NB;
    __shared__ float Ld[NB][NB + 1], RW[NB][NB + 1], invd[NB];
    int t = threadIdx.x;
    for (int l = 0; l < NB; l++) Ld[l][t] = Ab[(size_t)(kb + l) * TT + kb + t];
    for (int l = 0; l < NB; l++) RW[l][t] = Ab[(size_t)(r0 + l) * TT + kb + t];
    __syncthreads();
    invd[t] = 1.0f / Ld[t][t];
    __syncthreads();
    // thread t owns row t; right-looking forward substitution (ILP across p)
    for (int j = 0; j < NB; j++) {
        float xv = RW[t][j] * invd[j];
        RW[t][j] = xv;
        for (int p = j + 1; p < NB; p++) RW[t][p] -= Ld[p][j] * xv;
    }
    __syncthreads();
    for (int l = 0; l < NB; l++) Ab[(size_t)(r0 + l) * TT + kb + t] = RW[l][t];
}

// ---------------- Cholesky: trailing SYRK update (64x64 tiles) ----------------
__global__ __launch_bounds__(256) void k_chol_syrk(float* __restrict__ A, int k) {
    int ti = blockIdx.x, tj = blockIdx.y, bz = blockIdx.z;
    if (tj > ti) return;
    float* Ab = A + (size_t)bz * TT * TT;
    int kb = k * NB;
    int r0 = kb + NB;
    int rowA = r0 + ti * NB, rowB = r0 + tj * NB;
    __shared__ __align__(16) float At[NB][68];
    __shared__ __align__(16) float Bs[NB][68];
    int t = threadIdx.x;
    for (int l = 0; l < 16; l++) {
        int e = l * 256 + t; int r = e >> 6, c = e & 63;
        At[c][r] = Ab[(size_t)(rowA + r) * TT + kb + c];
        Bs[c][r] = Ab[(size_t)(rowB + r) * TT + kb + c];
    }
    __syncthreads();
    int tx = t & 15, ty = t >> 4;
    float acc[4][4] = {};
#pragma unroll 8
    for (int p = 0; p < NB; p++) {
        float4 av = *reinterpret_cast<const float4*>(&At[p][ty * 4]);
        float4 bv = *reinterpret_cast<const float4*>(&Bs[p][tx * 4]);
        float aa[4] = {av.x, av.y, av.z, av.w};
        float bb[4] = {bv.x, bv.y, bv.z, bv.w};
        for (int i = 0; i < 4; i++)
            for (int j = 0; j < 4; j++) acc[i][j] += aa[i] * bb[j];
    }
    for (int i = 0; i < 4; i++) {
        size_t row = (size_t)(rowA + ty * 4 + i) * TT + rowB + tx * 4;
        float4 cv = *reinterpret_cast<float4*>(&Ab[row]);
        cv.x -= acc[i][0]; cv.y -= acc[i][1]; cv.z -= acc[i][2]; cv.w -= acc[i][3];
        *reinterpret_cast<float4*>(&Ab[row]) = cv;
    }
}

// ---------------- big TRSM: diag solve (64 rows of G, all 1024 cols) ----------------
__global__ __launch_bounds__(256) void k_trsm_diag(const float* __restrict__ A,
                                                   float* __restrict__ G, int k) {
    int bz = blockIdx.y;
    const float* Ab = A + (size_t)bz * TT * TT;
    float* Gb = G + (size_t)bz * TT * TT;
    int kb = k * NB;
    __shared__ float Ld[NB][NB + 1];
    __shared__ float invd[NB];
    int t = threadIdx.x;
    for (int l = 0; l < 16; l++) {
        int e = l * 256 + t; int r = e >> 6, c = e & 63;
        Ld[r][c] = Ab[(size_t)(kb + r) * TT + kb + c];
    }
    __syncthreads();
    if (t < NB) invd[t] = 1.0f / Ld[t][t];
    __syncthreads();
    int cidx = blockIdx.x * 256 + t;
    float x[NB];
#pragma unroll
    for (int j = 0; j < NB; j++) x[j] = Gb[(size_t)(kb + j) * TT + cidx];
#pragma unroll
    for (int j = 0; j < NB; j++) {
        float s = x[j];
#pragma unroll
        for (int p = 0; p < j; p++) s -= Ld[j][p] * x[p];
        x[j] = s * invd[j];
    }
#pragma unroll
    for (int j = 0; j < NB; j++) Gb[(size_t)(kb + j) * TT + cidx] = x[j];
}

// ---------------- big TRSM: trailing GEMM update ----------------
__global__ __launch_bounds__(256) void k_trsm_update(const float* __restrict__ A,
                                                     float* __restrict__ G, int k) {
    int ti = blockIdx.x, tjc = blockIdx.y, bz = blockIdx.z;
    const float* Ab = A + (size_t)bz * TT * TT;
    float* Gb = G + (size_t)bz * TT * TT;
    int kb = k * NB;
    int rowA = kb + NB + ti * NB;
    int col0 = tjc * NB;
    __shared__ __align__(16) float At[NB][68];
    __shared__ __align__(16) float Bl[NB][68];
    int t = threadIdx.x;
    for (int l = 0; l < 16; l++) {
        int e = l * 256 + t; int r = e >> 6, c = e & 63;
        At[c][r] = Ab[(size_t)(rowA + r) * TT + kb + c];
        Bl[r][c] = Gb[(size_t)(kb + r) * TT + col0 + c];
    }
    __syncthreads();
    int tx = t & 15, ty = t >> 4;
    float acc[4][4] = {};
#pragma unroll 8
    for (int p = 0; p < NB; p++) {
        float4 av = *reinterpret_cast<const float4*>(&At[p][ty * 4]);
        float4 bv = *reinterpret_cast<const float4*>(&Bl[p][tx * 4]);
        float aa[4] = {av.x, av.y, av.z, av.w};
        float bb[4] = {bv.x, bv.y, bv.z, bv.w};
        for (int i = 0; i < 4; i++)
            for (int j = 0; j < 4; j++) acc[i][j] += aa[i] * bb[j];
    }
    for (int i = 0; i < 4; i++) {
        size_t row = (size_t)(rowA + ty * 4 + i) * TT + col0 + tx * 4;
        float4 cv = *reinterpret_cast<float4*>(&Gb[row]);
        cv.x -= acc[i][0]; cv.y -= acc[i][1]; cv.z -= acc[i][2]; cv.w -= acc[i][3];
        *reinterpret_cast<float4*>(&Gb[row]) = cv;
    }
}

// ---------------- forward solve z = L^{-1}(y - c) ----------------
__global__ __launch_bounds__(64) void k_fwd(const float* __restrict__ A,
                                            const float* __restrict__ values,
                                            const float* __restrict__ mc,
                                            float* __restrict__ zbuf, int b0) {
    int bz = blockIdx.x; int b = b0 + bz;
    const float* Ab = A + (size_t)bz * TT * TT;
    __shared__ float zl[TT];
    __shared__ float Ld[NB][NB + 1];
    __shared__ float invd[NB];
    int t = threadIdx.x;
    float c0 = mc[0];
    for (int i = t; i < TT; i += 64) zl[i] = values[b * TT + i] - c0;
    for (int k = 0; k < NSTEPS; k++) {
        int kb = k * NB;
        __syncthreads();
        for (int l = 0; l < NB; l++) Ld[l][t] = Ab[(size_t)(kb + l) * TT + kb + t];
        __syncthreads();
        invd[t] = 1.0f / Ld[t][t];
        __syncthreads();
        for (int j = 0; j < NB; j++) {
            if (t == j) zl[kb + j] *= invd[j];
            __syncthreads();
            if (t > j) zl[kb + t] -= Ld[t][j] * zl[kb + j];
        }
        __syncthreads();
        for (int r = kb + NB + t; r < TT; r += 64) {
            float acc = 0.f;
            for (int c = 0; c < NB; c++) acc += Ab[(size_t)r * TT + kb + c] * zl[kb + c];
            zl[r] -= acc;
        }
    }
    __syncthreads();
    for (int i = t; i < TT; i += 64) zbuf[b * TT + i] = zl[i];
}

// ---------------- backward solve alpha = L^{-T} z ----------------
__global__ __launch_bounds__(64) void k_bwd(const float* __restrict__ A,
                                            const float* __restrict__ zbuf,
                                            float* __restrict__ abuf, int b0) {
    int bz = blockIdx.x; int b = b0 + bz;
    const float* Ab = A + (size_t)bz * TT * TT;
    __shared__ float zl[TT];
    __shared__ float Ld[NB][NB + 1];
    __shared__ float invd[NB];
    int t = threadIdx.x;
    for (int i = t; i < TT; i += 64) zl[i] = zbuf[b * TT + i];
    for (int k = NSTEPS - 1; k >= 0; k--) {
        int kb = k * NB;
        __syncthreads();
        for (int l = 0; l < NB; l++) Ld[l][t] = Ab[(size_t)(kb + l) * TT + kb + t];
        __syncthreads();
        invd[t] = 1.0f / Ld[t][t];
        __syncthreads();
        for (int j = NB - 1; j >= 0; j--) {
            if (t == j) zl[kb + j] *= invd[j];
            __syncthreads();
            if (t < j) zl[kb + t] -= Ld[j][t] * zl[kb + j];
        }
        __syncthreads();
        for (int i = t; i < kb; i += 64) {
            float acc = 0.f;
            for (int j = 0; j < NB; j++) acc += Ab[(size_t)(kb + j) * TT + i] * zl[kb + j];
            zl[i] -= acc;
        }
    }
    __syncthreads();
    for (int i = t; i < TT; i += 64) abuf[b * TT + i] = zl[i];
}

// ---------------- mean = c + G^T alpha ----------------
__global__ __launch_bounds__(256) void k_mean(const float* __restrict__ G,
                                              const float* __restrict__ abuf,
                                              const float* __restrict__ mc,
                                              float* __restrict__ meanb, int b0) {
    int bz = blockIdx.y; int b = b0 + bz;
    const float* Gb = G + (size_t)bz * TT * TT;
    int i = blockIdx.x * 256 + threadIdx.x;
    float acc = 0.f;
    for (int j = 0; j < TT; j++) acc += Gb[(size_t)j * TT + i] * abuf[b * TT + j];
    meanb[b * TT + i] = mc[0] + acc;
}

// ---------------- cov = Kss - V^T V + JIT*I (lower tiles, into A) ----------------
__global__ __launch_bounds__(256) void k_cov(const float* __restrict__ G,
                                             const float* __restrict__ xs,
                                             const int* __restrict__ ite,
                                             const float* __restrict__ lsp,
                                             const float* __restrict__ Bt,
                                             float* __restrict__ A, int b0) {
    int ti = blockIdx.x, tj = blockIdx.y, bz = blockIdx.z;
    if (tj > ti) return;
    int b = b0 + bz;
    const float* Gb = G + (size_t)bz * TT * TT;
    float* Ab = A + (size_t)bz * TT * TT;
    int i0 = ti * NB, j0 = tj * NB;
    __shared__ __align__(16) float Ga[NB][68];
    __shared__ __align__(16) float Gc[NB][68];
    __shared__ float sxi[NB], sxj[NB], Btl[289];
    __shared__ int sei[NB], sej[NB];
    int t = threadIdx.x;
    if (t < 64) { sxi[t] = xs[b * TT + i0 + t]; sei[t] = ite[b * TT + i0 + t]; }
    else if (t < 128) { int u = t - 64; sxj[u] = xs[b * TT + j0 + u]; sej[u] = ite[b * TT + j0 + u]; }
    for (int e = t; e < 289; e += 256) Btl[e] = Bt[e];
    int tx = t & 15, ty = t >> 4;
    float acc[4][4] = {};
    for (int kk = 0; kk < TT; kk += NB) {
        __syncthreads();
        for (int l = 0; l < 16; l++) {
            int e = l * 256 + t; int r = e >> 6, c = e & 63;
            Ga[r][c] = Gb[(size_t)(kk + r) * TT + i0 + c];
            Gc[r][c] = Gb[(size_t)(kk + r) * TT + j0 + c];
        }
        __syncthreads();
#pragma unroll 8
        for (int p = 0; p < NB; p++) {
            float4 av = *reinterpret_cast<const float4*>(&Ga[p][ty * 4]);
            float4 bv = *reinterpret_cast<const float4*>(&Gc[p][tx * 4]);
            float aa[4] = {av.x, av.y, av.z, av.w};
            float bb[4] = {bv.x, bv.y, bv.z, bv.w};
            for (int i = 0; i < 4; i++)
                for (int j = 0; j < 4; j++) acc[i][j] += aa[i] * bb[j];
        }
    }
    float invls = 1.0f / lsp[0];
    for (int i = 0; i < 4; i++) {
        for (int j = 0; j < 4; j++) {
            int gi = i0 + ty * 4 + i, gj = j0 + tx * 4 + j;
            if (gi >= gj) {
                float d = (sxi[ty * 4 + i] - sxj[tx * 4 + j]) * invls;
                float kss = expf(-0.5f * d * d) * Btl[sei[ty * 4 + i] * 17 + sej[tx * 4 + j]];
                float v = kss - acc[i][j];
                if (gi == gj) v += JIT;
                Ab[(size_t)gi * TT + gj] = v;
            }
        }
    }
}

// ---------------- P[c][j] = sum_{i>=j, ch(i)=c} Lstar[i][j] ----------------
__global__ __launch_bounds__(256) void k_P(const float* __restrict__ A,
                                           const int* __restrict__ ite,
                                           float* __restrict__ P, int b0) {
    int bz = blockIdx.y; int b = b0 + bz;
    const float* Ab = A + (size_t)bz * TT * TT;
    __shared__ int chl[TT];
    __shared__ float accl[CH * 256];
    int t = threadIdx.x;
    for (int i = t; i < TT; i += 256) chl[i] = ite[b * TT + i];
    for (int c = 0; c < CH; c++) accl[c * 256 + t] = 0.f;
    __syncthreads();
    int j0 = blockIdx.x * 256;
    int j = j0 + t;
    for (int i = j0; i < TT; i++) {
        float v = Ab[(size_t)i * TT + j];
        if (i >= j) accl[chl[i] * 256 + t] += v;
    }
    for (int c = 0; c < CH; c++) P[((size_t)b * CH + c) * TT + j] = accl[c * 256 + t];
}

// ---------------- msum[c] = sum_{ch(i)=c} mean[i] ----------------
__global__ __launch_bounds__(64) void k_msum(const float* __restrict__ meanb,
                                             const int* __restrict__ ite,
                                             float* __restrict__ msum, int b0) {
    int bz = blockIdx.x; int b = b0 + bz;
    __shared__ float pacc[CH][65];
    int t = threadIdx.x;
    for (int c = 0; c < CH; c++) pacc[c][t] = 0.f;
    __syncthreads();
    for (int i = t; i < TT; i += 64) pacc[ite[b * TT + i]][t] += meanb[b * TT + i];
    __syncthreads();
    if (t < CH) {
        float s = 0.f;
        for (int u = 0; u < 64; u++) s += pacc[t][u];
        msum[b * CH + t] = s;
    }
}

// ---------------- feat + classifier head ----------------
__global__ __launch_bounds__(256) void k_featout(const float* __restrict__ P,
                                                 const float* __restrict__ msum,
                                                 const float* __restrict__ eps,
                                                 const float* __restrict__ Wc,
                                                 const float* __restrict__ bc,
                                                 float* __restrict__ out, int b0, int Btot) {
    int s = blockIdx.x; int b = b0 + blockIdx.y;
    __shared__ float el[TT];
    __shared__ float part[256];
    __shared__ float featl[CH];
    int t = threadIdx.x;
    for (int i = t; i < TT; i += 256) el[i] = eps[((size_t)s * Btot + b) * TT + i];
    __syncthreads();
    int c = t >> 4, seg = t & 15;
    float acc = 0.f;
    const float* Pr = &P[((size_t)b * CH + c) * TT + seg * 64];
    for (int j = 0; j < 64; j++) acc += Pr[j] * el[seg * 64 + j];
    part[t] = acc;
    __syncthreads();
    if (t < CH) {
        float s2 = msum[b * CH + t];
        for (int g = 0; g < 16; g++) s2 += part[t * 16 + g];
        featl[t] = s2 * (1.0f / 64.0f);
    }
    __syncthreads();
    if (t < NCLS) {
        float o = bc[t];
        for (int c2 = 0; c2 < CH; c2++) o += featl[c2] * Wc[c2 * NCLS + t];
        out[((size_t)s * Btot + b) * NCLS + t] = o;
    }
}

extern "C" void kernel_launch(void* const* d_in, const int* in_sizes, int n_in,
                              void* d_out, int out_size, void* d_ws, size_t ws_size,
                              hipStream_t stream) {
    const float* inputs       = (const float*)d_in[0];
    const float* values       = (const float*)d_in[1];
    const float* test_inputs  = (const float*)d_in[2];
    const float* eps          = (const float*)d_in[3];
    const float* mc           = (const float*)d_in[4];
    const float* ls           = (const float*)d_in[5];
    const float* noise        = (const float*)d_in[6];
    const float* W_task       = (const float*)d_in[7];
    const float* v_task       = (const float*)d_in[8];
    const float* W_clf        = (const float*)d_in[9];
    const float* b_clf        = (const float*)d_in[10];
    const int*   indices      = (const int*)d_in[11];
    const int*   test_indices = (const int*)d_in[12];
    float* out = (float*)d_out;

    int Btot = in_sizes[1] / TT;   // 32

    float* ws = (float*)d_ws;
    size_t off = 0;
    float* Bt    = ws + off; off += 512;
    float* zbuf  = ws + off; off += (size_t)Btot * TT;
    float* abuf  = ws + off; off += (size_t)Btot * TT;
    float* meanb = ws + off; off += (size_t)Btot * TT;
    float* Pb    = ws + off; off += (size_t)Btot * CH * TT;
    float* msum  = ws + off; off += (size_t)Btot * CH;
    off = (off + 63) & ~(size_t)63;

    size_t avail = (ws_size / 4 > off) ? (ws_size / 4 - off) : 0;
    size_t per = 2 * (size_t)TT * TT;
    int chunk = (int)(avail / per);
    if (chunk < 1) chunk = 1;
    if (chunk > Btot) chunk = Btot;
    float* bigA = ws + off;
    float* bigG = bigA + (size_t)chunk * TT * TT;

    k_btask<<<1, 256, 0, stream>>>(W_task, v_task, Bt);

    for (int b0 = 0; b0 < Btot; b0 += chunk) {
        int bc = chunk; if (b0 + bc > Btot) bc = Btot - b0;

        // ---- Kxx and its Cholesky ----
        k_build_kxx<<<dim3(8, 8, bc), 256, 0, stream>>>(inputs, indices, ls, noise, Bt, bigA, b0);
        for (int k = 0; k < NSTEPS; k++) {
            k_chol_diag<<<bc, 64, 0, stream>>>(bigA, k);
            int m = NSTEPS - 1 - k;
            if (m > 0) {
                k_chol_trsm<<<dim3(m, bc), 64, 0, stream>>>(bigA, k);
                k_chol_syrk<<<dim3(m, m, bc), 256, 0, stream>>>(bigA, k);
            }
        }
        // ---- alpha = Kxx^{-1}(y-c) ----
        k_fwd<<<bc, 64, 0, stream>>>(bigA, values, mc, zbuf, b0);
        k_bwd<<<bc, 64, 0, stream>>>(bigA, zbuf, abuf, b0);
        // ---- G = Ksx^T, mean ----
        k_build_g<<<dim3(8, 8, bc), 256, 0, stream>>>(test_inputs, inputs, test_indices, indices, ls, Bt, bigG, b0);
        k_mean<<<dim3(4, bc), 256, 0, stream>>>(bigG, abuf, mc, meanb, b0);
        // ---- V = L^{-1} G (in place) ----
        for (int k = 0; k < NSTEPS; k++) {
            k_trsm_diag<<<dim3(4, bc), 256, 0, stream>>>(bigA, bigG, k);
            int m = NSTEPS - 1 - k;
            if (m > 0) k_trsm_update<<<dim3(m, 16, bc), 256, 0, stream>>>(bigA, bigG, k);
        }
        // ---- cov -> A, chol(cov) ----
        k_cov<<<dim3(16, 16, bc), 256, 0, stream>>>(bigG, test_inputs, test_indices, ls, Bt, bigA, b0);
        for (int k = 0; k < NSTEPS; k++) {
            k_chol_diag<<<bc, 64, 0, stream>>>(bigA, k);
            int m = NSTEPS - 1 - k;
            if (m > 0) {
                k_chol_trsm<<<dim3(m, bc), 64, 0, stream>>>(bigA, k);
                k_chol_syrk<<<dim3(m, m, bc), 256, 0, stream>>>(bigA, k);
            }
        }
        // ---- pooled sampling + classifier ----
        k_P<<<dim3(4, bc), 256, 0, stream>>>(bigA, test_indices, Pb, b0);
        k_msum<<<bc, 64, 0, stream>>>(meanb, test_indices, msum, b0);
        k_featout<<<dim3(SMC, bc), 256, 0, stream>>>(Pb, msum, eps, W_clf, b_clf, out, b0, Btot);
    }
}